// Round 4
// baseline (2748.248 us; speedup 1.0000x reference)
//
#include <hip/hip_runtime.h>

// Problem constants: B=128, T=512, D=1024, H=128, 4H=512.
#define BATCH 128
#define TSTEPS 512
#define HID 128
#define GATES 512
#define M_TOTAL (BATCH*TSTEPS)   // 65536

typedef _Float16 half8 __attribute__((ext_vector_type(8)));
typedef float    f32x4 __attribute__((ext_vector_type(4)));

__device__ __forceinline__ float sigmoidf_fast(float x){ return 1.0f/(1.0f+__expf(-x)); }
__device__ __forceinline__ float tanhf_fast(float x){ return 1.0f - 2.0f/(__expf(2.0f*x)+1.0f); }

__device__ __forceinline__ half8 cvt_h8(const float* s){
    half8 r;
    #pragma unroll
    for (int j=0;j<8;++j) r[j] = (_Float16)s[j];
    return r;
}

__device__ __forceinline__ void spin_ge(const int* p, int v){
    while (__hip_atomic_load(p, __ATOMIC_ACQUIRE, __HIP_MEMORY_SCOPE_AGENT) < v)
        __builtin_amdgcn_s_sleep(2);
}

// ---------------------------------------------------------------------------
// Preconvert w_ih0 (512x1024 fp32) to f16 hi/lo split.
// ---------------------------------------------------------------------------
__global__ __launch_bounds__(256) void convert_w(
    const float* __restrict__ src, _Float16* __restrict__ hi, _Float16* __restrict__ lo)
{
    const int i = blockIdx.x*256 + threadIdx.x;   // x4 elements
    float4 v = ((const float4*)src)[i];
    union { _Float16 h[4]; unsigned long long u; } H, L;
    H.h[0]=(_Float16)v.x; H.h[1]=(_Float16)v.y; H.h[2]=(_Float16)v.z; H.h[3]=(_Float16)v.w;
    L.h[0]=(_Float16)(v.x-(float)H.h[0]); L.h[1]=(_Float16)(v.y-(float)H.h[1]);
    L.h[2]=(_Float16)(v.z-(float)H.h[2]); L.h[3]=(_Float16)(v.w-(float)H.h[3]);
    ((unsigned long long*)hi)[i] = H.u;
    ((unsigned long long*)lo)[i] = L.u;
}

// ---------------------------------------------------------------------------
// Mega-kernel: blocks 0..7 producer rec (layer0, 16 batches each),
// blocks 8..15 consumer rec (layer1 + FC), blocks 16..1039 GEMM (256x128 tile,
// f16 hi/lo split, t-major order, signals tccnt[2] epochs of 256 steps).
// GEMM blocks never wait => deadlock-free under any scheduling.
// xg layout: [t][b][n] fp32 (biases folded).  h1g: per producer, per step,
// a 4KB f16 image of the A-fragment-layout h tile.
// ---------------------------------------------------------------------------
__global__ __launch_bounds__(512, 2) void mega(
    const float* __restrict__ x,
    const _Float16* __restrict__ Wh, const _Float16* __restrict__ Wl,
    const float* __restrict__ b_ih0, const float* __restrict__ b_hh0,
    const float* __restrict__ w_hh0,
    const float* __restrict__ w_ih1, const float* __restrict__ w_hh1,
    const float* __restrict__ b_ih1, const float* __restrict__ b_hh1,
    const float* __restrict__ fc_w,  const float* __restrict__ fc_b,
    float* __restrict__ xg,          // [512][128][512]
    _Float16* __restrict__ h1g,      // [8][512][2048]
    int* __restrict__ tccnt,         // [2]
    int* __restrict__ flagP,         // [8]
    float* __restrict__ out)         // [128][8]
{
    __shared__ __align__(16) char smem[49152];
    const int tid  = threadIdx.x;
    const int lane = tid & 63;
    const int wv   = tid >> 6;
    const int m15  = lane & 15;
    const int sub  = lane >> 4;
    const int bx   = blockIdx.x;

    if (bx >= 16) {
        // ======================= GEMM =======================
        const int id  = bx - 16;
        const int xn  = id & 3;
        const int ym  = id >> 2;      // 0..255, tc2-major after split:
        const int bb  = ym & 127;
        const int tc2 = ym >> 7;      // 0..1  (ids 0..511 are tc2=0 -> dispatched first)
        const int m0  = bb*512 + tc2*256;
        const int n0  = xn*128;

        _Float16* sXh = (_Float16*)smem;             // 256x32
        _Float16* sXl = (_Float16*)(smem + 16384);
        _Float16* sWh = (_Float16*)(smem + 32768);   // 128x32
        _Float16* sWl = (_Float16*)(smem + 40960);

        const int wm = wv & 3, wn = wv >> 2;
        const int ar = tid & 255, akb2 = (tid >> 8) * 2;
        const float* pA = x + (size_t)(m0 + ar)*1024 + (tid >> 8)*16;
        const int wr = tid & 127, wkb = tid >> 7;
        const _Float16* pWh = Wh + (size_t)(n0 + wr)*1024 + wkb*8;
        const _Float16* pWl = Wl + (size_t)(n0 + wr)*1024 + wkb*8;

        f32x4 acc[4][4];
        #pragma unroll
        for (int nt=0;nt<4;++nt){
            const int cn = n0 + wn*64 + nt*16 + m15;
            const float bv = b_ih0[cn] + b_hh0[cn];
            #pragma unroll
            for (int mt=0;mt<4;++mt) acc[mt][nt] = (f32x4){bv,bv,bv,bv};
        }

        float xv[16];
        #pragma unroll
        for (int j=0;j<4;++j) *(float4*)&xv[4*j] = *(const float4*)(pA + 4*j);
        half8 whv = *(const half8*)pWh;
        half8 wlv = *(const half8*)pWl;

        for (int ks=0; ks<32; ++ks) {
            half8 hh0, hh1, hl0, hl1;
            #pragma unroll
            for (int j=0;j<8;++j){ _Float16 h=(_Float16)xv[j];   hh0[j]=h; hl0[j]=(_Float16)(xv[j]-(float)h); }
            #pragma unroll
            for (int j=0;j<8;++j){ _Float16 h=(_Float16)xv[8+j]; hh1[j]=h; hl1[j]=(_Float16)(xv[8+j]-(float)h); }
            if (ks) __syncthreads();
            *(half8*)&sXh[(size_t)((akb2  )*256 + ar)*8] = hh0;
            *(half8*)&sXh[(size_t)((akb2+1)*256 + ar)*8] = hh1;
            *(half8*)&sXl[(size_t)((akb2  )*256 + ar)*8] = hl0;
            *(half8*)&sXl[(size_t)((akb2+1)*256 + ar)*8] = hl1;
            *(half8*)&sWh[(size_t)(wkb*128 + wr)*8] = whv;
            *(half8*)&sWl[(size_t)(wkb*128 + wr)*8] = wlv;
            __syncthreads();
            if (ks < 31) {
                const int kn = (ks+1)*32;
                #pragma unroll
                for (int j=0;j<4;++j) *(float4*)&xv[4*j] = *(const float4*)(pA + kn + 4*j);
                whv = *(const half8*)(pWh + kn);
                wlv = *(const half8*)(pWl + kn);
            }
            half8 ah[4], al[4], bh[4], bl[4];
            #pragma unroll
            for (int mt=0;mt<4;++mt){
                const int idx = (sub*256 + wm*64 + mt*16 + m15)*8;
                ah[mt] = *(const half8*)&sXh[idx];
                al[mt] = *(const half8*)&sXl[idx];
            }
            #pragma unroll
            for (int nt=0;nt<4;++nt){
                const int idx = (sub*128 + wn*64 + nt*16 + m15)*8;
                bh[nt] = *(const half8*)&sWh[idx];
                bl[nt] = *(const half8*)&sWl[idx];
            }
            #pragma unroll
            for (int mt=0;mt<4;++mt)
                #pragma unroll
                for (int nt=0;nt<4;++nt){
                    acc[mt][nt]=__builtin_amdgcn_mfma_f32_16x16x32_f16(ah[mt],bh[nt],acc[mt][nt],0,0,0);
                    acc[mt][nt]=__builtin_amdgcn_mfma_f32_16x16x32_f16(ah[mt],bl[nt],acc[mt][nt],0,0,0);
                    acc[mt][nt]=__builtin_amdgcn_mfma_f32_16x16x32_f16(al[mt],bh[nt],acc[mt][nt],0,0,0);
                }
        }
        #pragma unroll
        for (int mt=0;mt<4;++mt){
            #pragma unroll
            for (int r=0;r<4;++r){
                const int rm = m0 + wm*64 + mt*16 + sub*4 + r;
                float* orow = xg + ((size_t)(rm & 511)*128 + (rm >> 9))*512;
                #pragma unroll
                for (int nt=0;nt<4;++nt)
                    orow[n0 + wn*64 + nt*16 + m15] = acc[mt][nt][r];
            }
        }
        __syncthreads();   // drain all waves' xg stores before signaling
        if (tid == 0)
            __hip_atomic_fetch_add(&tccnt[tc2], 1, __ATOMIC_RELEASE, __HIP_MEMORY_SCOPE_AGENT);
        return;
    }

    // ======================= recurrence =======================
    const bool L1 = bx >= 8;
    const int p  = bx & 7;
    const int B0 = p * 16;

    _Float16* hA   = (_Float16*)smem;                 // [16 kc][16 m][8] f16 = 4KB
    float*    actS = (float*)(smem + 4096);           // 16x512 f32, XOR-swizzled cols
    float*    hfin = (float*)(smem + 36864);          // 16x128 f32 (consumer, last step)

    const int wn0 = wv * 64;

    // B-fragments in registers: lane holds B[k=sub*8+j][n=wn0+nt*16+m15] = W[n][k]
    half8 whhF[4][4], wihF[4][4];
    {
        const float* wsrc = L1 ? w_hh1 : w_hh0;
        #pragma unroll
        for (int nt=0;nt<4;++nt)
            #pragma unroll
            for (int kf=0;kf<4;++kf)
                whhF[nt][kf] = cvt_h8(wsrc + (size_t)(wn0+nt*16+m15)*HID + kf*32 + sub*8);
    }
    float bc[4] = {0,0,0,0};
    if (L1) {
        #pragma unroll
        for (int nt=0;nt<4;++nt)
            #pragma unroll
            for (int kf=0;kf<4;++kf)
                wihF[nt][kf] = cvt_h8(w_ih1 + (size_t)(wn0+nt*16+m15)*HID + kf*32 + sub*8);
        #pragma unroll
        for (int nt=0;nt<4;++nt){
            const int cn = wn0 + nt*16 + m15;
            bc[nt] = b_ih1[cn] + b_hh1[cn];
        }
    }

    const int me = tid & 15;       // elementwise batch row
    const int hq = tid >> 4;       // 0..31, hid = hq + 32q
    float c4[4] = {0,0,0,0};

    ((unsigned long long*)hA)[tid & 511] = 0ULL;   // zero h_0 (4KB)

    _Float16* h1b = h1g + (size_t)p * TSTEPS * 2048;

    f32x4 xc[4], xnx[4];
    half8 a2c[4], a2n[4];
    int seen = 0;

    if (!L1) {
        spin_ge(&tccnt[0], 512);   // all of t-epoch 0 ready
        #pragma unroll
        for (int nt=0;nt<4;++nt)
            #pragma unroll
            for (int r=0;r<4;++r)
                xc[nt][r] = xg[((size_t)0*128 + B0 + sub*4 + r)*512 + wn0 + nt*16 + m15];
    } else {
        while ((seen = __hip_atomic_load(&flagP[p], __ATOMIC_ACQUIRE, __HIP_MEMORY_SCOPE_AGENT)) < 1)
            __builtin_amdgcn_s_sleep(2);
        #pragma unroll
        for (int kf=0;kf<4;++kf)
            a2c[kf] = *(const half8*)&h1b[((kf*4+sub)*16 + m15)*8];
    }
    __syncthreads();

    for (int t=0; t<TSTEPS; ++t) {
        f32x4 acc[4];
        if (!L1){
            #pragma unroll
            for (int nt=0;nt<4;++nt) acc[nt] = xc[nt];
            if (t < TSTEPS-1 && ((t+1) & 255) != 0) {   // prefetch xg for t+1 (same epoch)
                #pragma unroll
                for (int nt=0;nt<4;++nt)
                    #pragma unroll
                    for (int r=0;r<4;++r)
                        xnx[nt][r] = xg[((size_t)(t+1)*128 + B0 + sub*4 + r)*512 + wn0 + nt*16 + m15];
            }
        } else {
            #pragma unroll
            for (int nt=0;nt<4;++nt) acc[nt] = (f32x4){bc[nt],bc[nt],bc[nt],bc[nt]};
            if (t < TSTEPS-1) {                          // prefetch h0 frag for t+1
                if (seen < t+2) {
                    while ((seen = __hip_atomic_load(&flagP[p], __ATOMIC_ACQUIRE, __HIP_MEMORY_SCOPE_AGENT)) < t+2)
                        __builtin_amdgcn_s_sleep(2);
                }
                const _Float16* src = h1b + (size_t)(t+1)*2048;
                #pragma unroll
                for (int kf=0;kf<4;++kf)
                    a2n[kf] = *(const half8*)&src[((kf*4+sub)*16 + m15)*8];
            }
        }

        // own-h A fragments + MFMA
        half8 aF[4];
        #pragma unroll
        for (int kf=0;kf<4;++kf)
            aF[kf] = *(const half8*)&hA[((kf*4+sub)*16 + m15)*8];
        #pragma unroll
        for (int nt=0;nt<4;++nt)
            #pragma unroll
            for (int kf=0;kf<4;++kf)
                acc[nt] = __builtin_amdgcn_mfma_f32_16x16x32_f16(aF[kf], whhF[nt][kf], acc[nt], 0,0,0);
        if (L1) {
            #pragma unroll
            for (int nt=0;nt<4;++nt)
                #pragma unroll
                for (int kf=0;kf<4;++kf)
                    acc[nt] = __builtin_amdgcn_mfma_f32_16x16x32_f16(a2c[kf], wihF[nt][kf], acc[nt], 0,0,0);
        }

        // activations -> actS (col XOR-swizzle kills bank conflicts)
        const bool isG = ((wv >> 1) == 2);   // gates n in [256,384) are tanh
        #pragma unroll
        for (int nt=0;nt<4;++nt){
            #pragma unroll
            for (int r=0;r<4;++r){
                const float v = acc[nt][r];
                const float a = isG ? tanhf_fast(v) : sigmoidf_fast(v);
                const int mw = sub*4 + r;
                actS[mw*512 + ((wn0 + nt*16 + m15) ^ ((mw & 7) << 2))] = a;
            }
        }
        __syncthreads();

        // elementwise c/h update; h written to hA in A-frag layout
        #pragma unroll
        for (int q=0;q<4;++q){
            const int hid = hq + 32*q;
            const int sw = (me & 7) << 2;
            const float ig = actS[me*512 + ((hid      ) ^ sw)];
            const float fg = actS[me*512 + ((hid + 128) ^ sw)];
            const float gg = actS[me*512 + ((hid + 256) ^ sw)];
            const float og = actS[me*512 + ((hid + 384) ^ sw)];
            c4[q] = __fmaf_rn(fg, c4[q], ig*gg);
            const float h = og * tanhf_fast(c4[q]);
            hA[((hid>>3)*16 + me)*8 + (hid & 7)] = (_Float16)h;
            if (L1 && t == TSTEPS-1) hfin[me*128 + hid] = h;
        }
        __syncthreads();

        if (!L1) {
            // publish the 4KB hA image (agent-scope b64 stores, coalesced)
            unsigned long long v = ((const unsigned long long*)hA)[tid];
            __hip_atomic_store(((unsigned long long*)(h1b + (size_t)t*2048)) + tid, v,
                               __ATOMIC_RELAXED, __HIP_MEMORY_SCOPE_AGENT);
            if ((t & 3) == 3) {
                __syncthreads();   // drains every wave's h1g stores (vmcnt before s_barrier)
                if (tid == 0)
                    __hip_atomic_store(&flagP[p], t+1, __ATOMIC_RELEASE, __HIP_MEMORY_SCOPE_AGENT);
            }
            if (t < TSTEPS-1) {
                if (((t+1) & 255) == 0) {          // epoch boundary: wait for GEMM
                    spin_ge(&tccnt[(t+1) >> 8], 512);
                    #pragma unroll
                    for (int nt=0;nt<4;++nt)
                        #pragma unroll
                        for (int r=0;r<4;++r)
                            xc[nt][r] = xg[((size_t)(t+1)*128 + B0 + sub*4 + r)*512 + wn0 + nt*16 + m15];
                } else {
                    #pragma unroll
                    for (int nt=0;nt<4;++nt) xc[nt] = xnx[nt];
                }
            }
        } else {
            #pragma unroll
            for (int kf=0;kf<4;++kf) a2c[kf] = a2n[kf];
        }
    }

    if (L1) {
        __syncthreads();
        if (tid < 128) {
            const int mm = tid >> 3, o = tid & 7;
            float s = fc_b[o];
            const float* wrow = fc_w + o*HID;
            #pragma unroll 8
            for (int k=0;k<HID;++k) s = __fmaf_rn(wrow[k], hfin[mm*128 + k], s);
            out[(B0 + mm)*8 + o] = s;
        }
    }
}

// ---------------------------------------------------------------------------
extern "C" void kernel_launch(void* const* d_in, const int* in_sizes, int n_in,
                              void* d_out, int out_size, void* d_ws, size_t ws_size,
                              hipStream_t stream) {
    const float* x     = (const float*)d_in[0];
    const float* w_ih0 = (const float*)d_in[1];
    const float* w_hh0 = (const float*)d_in[2];
    const float* b_ih0 = (const float*)d_in[3];
    const float* b_hh0 = (const float*)d_in[4];
    const float* w_ih1 = (const float*)d_in[5];
    const float* w_hh1 = (const float*)d_in[6];
    const float* b_ih1 = (const float*)d_in[7];
    const float* b_hh1 = (const float*)d_in[8];
    const float* fc_w  = (const float*)d_in[9];
    const float* fc_b  = (const float*)d_in[10];
    float* out = (float*)d_out;

    // ws: xg 128MB | Wh 1MB | Wl 1MB | h1g 16MB | flags
    char* ws = (char*)d_ws;
    float*    xgp  = (float*)ws;
    size_t off = (size_t)M_TOTAL * GATES * 4;
    _Float16* Whp  = (_Float16*)(ws + off); off += (size_t)GATES*1024*2;
    _Float16* Wlp  = (_Float16*)(ws + off); off += (size_t)GATES*1024*2;
    _Float16* h1g  = (_Float16*)(ws + off); off += (size_t)8*TSTEPS*2048*2;
    int*      flags = (int*)(ws + off);     // tccnt[2] at flags, flagP[8] at flags+8

    hipMemsetAsync(flags, 0, 256, stream);
    convert_w<<<dim3(512), dim3(256), 0, stream>>>(w_ih0, Whp, Wlp);
    mega<<<dim3(16 + 1024), dim3(512), 0, stream>>>(
        x, Whp, Wlp, b_ih0, b_hh0, w_hh0, w_ih1, w_hh1, b_ih1, b_hh1,
        fc_w, fc_b, xgp, h1g, flags, flags + 8, out);
}